// Round 13
// baseline (240.885 us; speedup 1.0000x reference)
//
#include <hip/hip_runtime.h>
#include <stdint.h>

typedef unsigned short u16;
typedef unsigned int   u32;
typedef float f32x4  __attribute__((ext_vector_type(4)));
typedef float f32x16 __attribute__((ext_vector_type(16)));
typedef short s16x8  __attribute__((ext_vector_type(8)));

#define T_SEQ 2048
#define NE    2048
#define NH    16
#define NKV   4
#define HD    128
#define QKVW  3072   // fused qkv row width

__device__ __forceinline__ u16 f2bf(float f){
  u32 u = __float_as_uint(f);
  u32 r = u + 0x7FFFu + ((u >> 16) & 1u);   // RNE
  return (u16)(r >> 16);
}
__device__ __forceinline__ float bf2f(u16 h){ return __uint_as_float(((u32)h) << 16); }

// packed f32x2 -> bf16x2 (RNE), no builtin on gfx950
__device__ __forceinline__ u32 pkbf(float a, float b){
  u32 r; asm("v_cvt_pk_bf16_f32 %0, %1, %2" : "=v"(r) : "v"(a), "v"(b)); return r;
}

typedef __attribute__((address_space(3))) u32 lds_u32;
typedef __attribute__((address_space(1))) u32 glb_u32;
__device__ __forceinline__ void g2lds16(const void* g, void* l){
  __builtin_amdgcn_global_load_lds((const glb_u32*)g, (lds_u32*)l, 16, 0, 0);
}

// ================= fused prep: x cvt + 4 weight transposes + rope tables =================
#define PREP_NBLK 18944
__global__ __launch_bounds__(256) void k_prep(const float* __restrict__ x,
                                              const float* __restrict__ wq, const float* __restrict__ wk,
                                              const float* __restrict__ wv, const float* __restrict__ wo,
                                              u16* __restrict__ xb, u16* __restrict__ wqkvT, u16* __restrict__ woT,
                                              float* __restrict__ cosT, float* __restrict__ sinT){
  __shared__ float t[32][33];
  const int blk = blockIdx.x, tid = threadIdx.x;
  if (blk < 8192){                                   // ---- x fp32 -> bf16
    int i = (blk * 256 + tid) * 4;
    float4 v = *(const float4*)(x + i);
    ushort4 o; o.x = f2bf(v.x); o.y = f2bf(v.y); o.z = f2bf(v.z); o.w = f2bf(v.w);
    *(ushort4*)(xb + i) = o;
    return;
  }
  if (blk >= 18432){                                 // ---- rope tables [T][64]
    int i = (blk - 18432) * 256 + tid;               // t*64 + j
    int tt = i >> 6, j = i & 63;
    float inv = expf(-(float)j * (11.512925464970229f / 64.0f));  // ln(1e5)
    float f = (float)tt * inv;
    cosT[i] = cosf(f);
    sinT[i] = sinf(f);
    return;
  }
  // ---- weight transpose+convert W[R=2048][C] -> WT[C][2048]
  const float* in; u16* out; int C; int tt;
  if      (blk < 12288){ in = wq; out = wqkvT;                     C = 2048; tt = blk - 8192;  }
  else if (blk < 13312){ in = wk; out = wqkvT + (size_t)2048*2048; C = 512;  tt = blk - 12288; }
  else if (blk < 14336){ in = wv; out = wqkvT + (size_t)2560*2048; C = 512;  tt = blk - 13312; }
  else                 { in = wo; out = woT;                       C = 2048; tt = blk - 14336; }
  const int r0 = (tt & 63) * 32, c0 = (tt >> 6) * 32;
  const int tx = tid & 31, ty = tid >> 5;
  #pragma unroll
  for (int i = 0; i < 4; ++i) t[ty + i*8][tx] = in[(size_t)(r0 + ty + i*8) * C + c0 + tx];
  __syncthreads();
  #pragma unroll
  for (int i = 0; i < 4; ++i) out[(size_t)(c0 + ty + i*8) * 2048 + r0 + tx] = f2bf(t[tx][ty + i*8]);
}

// ================= fused post: rope(q) + rope(k) + V transpose =================
#define POST_NBLK 22528
__global__ __launch_bounds__(256) void k_post(u16* __restrict__ qkv, u16* __restrict__ vtb,
                                              const float* __restrict__ cosT, const float* __restrict__ sinT,
                                              float qscale){
  __shared__ u16 tsh[32][33];
  const int blk = blockIdx.x, tid = threadIdx.x;
  if (blk < 20480){                                  // ---- RoPE + RMS-norm in place
    u16* base; int log2h; float scale; int rh;
    if (blk < 16384){ base = qkv;        log2h = 4; scale = qscale; rh = blk * 4 + (tid >> 6); }
    else            { base = qkv + 2048; log2h = 2; scale = 1.0f;   rh = (blk - 16384) * 4 + (tid >> 6); }
    const int lane = tid & 63;
    const int row = rh >> log2h;                     // b*T + t
    const int h   = rh & ((1 << log2h) - 1);
    const int t   = row & (T_SEQ - 1);
    u16* p = base + (size_t)row * QKVW + h * HD;
    float x1 = bf2f(p[lane]), x2 = bf2f(p[lane + 64]);
    float c = cosT[t * 64 + lane], s = sinT[t * 64 + lane];
    float y1 = x1 * c + x2 * s;
    float y2 = x2 * c - x1 * s;
    float sq = y1 * y1 + y2 * y2;
    #pragma unroll
    for (int off = 32; off; off >>= 1) sq += __shfl_xor(sq, off);
    float sc = rsqrtf(sq * (1.0f / 128.0f) + 1e-6f) * scale;
    p[lane]      = f2bf(y1 * sc);
    p[lane + 64] = f2bf(y2 * sc);
    return;
  }
  // ---- V transpose: per b, qkv[t][2560+c] -> vtb[b][c][t]
  const int tt = blk - 20480;
  const int r0 = (tt & 63) * 32, c0 = ((tt >> 6) & 15) * 32, b = tt >> 10;
  const u16* ib = qkv + (size_t)b * T_SEQ * QKVW + 2560;
  u16*       ob = vtb + (size_t)b * 512 * T_SEQ;
  const int tx = tid & 31, ty = tid >> 5;
  #pragma unroll
  for (int i = 0; i < 4; ++i) tsh[ty + i*8][tx] = ib[(size_t)(r0 + ty + i*8) * QKVW + c0 + tx];
  __syncthreads();
  #pragma unroll
  for (int i = 0; i < 4; ++i) ob[(size_t)(c0 + ty + i*8) * T_SEQ + r0 + tx] = tsh[tx][ty + i*8];
}

// ================= GEMM: 128x256 tile, 4 waves (wave tile 128x64), BK=64 as 2 half-units,
// 3-slot LDS ring, counted vmcnt(6) — schedule identical to R9-validated ring, geometry scaled.
// Slot = A-half (128r x 32k, 8KB) + B-half (256r x 32k, 16KB). 72KB LDS -> 2 blocks/CU.
// Per half-unit per wave: A 2 + B 4 staging calls (6 in flight), 12 ds_read_b128, 32 MFMA.
__device__ __forceinline__ void cstore(u16* C, size_t i, float v){ C[i] = f2bf(v); }
__device__ __forceinline__ void cstore(float* C, size_t i, float v){ C[i] = v; }

template <int NCALL>
__device__ __forceinline__ void stage_half(const u16* __restrict__ G, int row0, int K, int k0,
                                           u16* lds, int w, int lane){
  #pragma unroll
  for (int call = 0; call < NCALL; ++call){
    const int o  = call * 256 + w * 64 + lane;   // chunk index
    const int rp = o >> 3, sl = o & 7;
    const int lg = sl ^ (rp & 7);                // logical (h,kc) within row-pair
    const int row = rp * 2 + (lg >> 2);
    const int kc  = lg & 3;
    // LDS dest is wave-uniform base + lane*16 (HW adds lane offset)
    g2lds16(G + (size_t)(row0 + row) * K + k0 + kc * 8, lds + (size_t)(call * 256 + w * 64) * 8);
  }
}

__device__ __forceinline__ s16x8 ldsFrag(const u16* slotBase, int row, int kchunk){
  const int byte = (row >> 1) * 128 + (((((row & 1) << 2) | kchunk) ^ ((row >> 1) & 7)) << 4);
  return *(const s16x8*)((const char*)slotBase + byte);
}

template <typename CT>
__global__ __launch_bounds__(256, 2) void k_gemm(const u16* __restrict__ A, const u16* __restrict__ BT,
                                                 CT* __restrict__ C, int M, int N, int K){
  __shared__ u16 As[3 * 4096];   // 3 slots x 8KB  (A: 128 rows)
  __shared__ u16 Bs[3 * 8192];   // 3 slots x 16KB (B: 256 rows)
  const int tid  = threadIdx.x;
  const int lane = tid & 63;
  const int w    = tid >> 6;                 // wave 0..3, owns cols [w*64, w*64+64)
  // T1 bijective XCD swizzle, m-fastest: each XCD owns 4 M-panels (2MB A-slice L2-resident)
  const int bid = blockIdx.x;
  const int xcd = bid & 7, ii = bid >> 3;
  const int mtile = xcd * 4 + (ii & 3);
  const int ntile = ii >> 2;
  const int tm0 = mtile * 128, tn0 = ntile * 256;
  const int frow = lane & 15, fk = lane >> 4;

  f32x4 acc[8][4] = {};
  const int nkt = K >> 6;

  // prologue: units 0,1 -> slots 0,1
  stage_half<2>(A,  tm0, K, 0,  As,        w, lane);
  stage_half<4>(BT, tn0, K, 0,  Bs,        w, lane);
  stage_half<2>(A,  tm0, K, 32, As + 4096, w, lane);
  stage_half<4>(BT, tn0, K, 32, Bs + 8192, w, lane);
  asm volatile("s_waitcnt vmcnt(6)" ::: "memory");
  __builtin_amdgcn_s_barrier();

  int s = 0;
  #pragma unroll 1
  for (int t = 0; t < nkt; ++t){
    const int s1 = (s + 1 > 2) ? 0 : s + 1;
    const int s2 = (s + 2 > 2) ? s - 1 : s + 2;
    const bool more = (t + 1 < nkt);

    if (more){                       // stage unit u+2 (tile t+1, k-half 0) -> slot s2
      stage_half<2>(A,  tm0, K, (t + 1) * 64,  As + s2 * 4096, w, lane);
      stage_half<4>(BT, tn0, K, (t + 1) * 64,  Bs + s2 * 8192, w, lane);
    }
    {                                 // compute k0 from slot s
      const u16* Ap = As + s * 4096;
      const u16* Bp = Bs + s * 8192;
      s16x8 af[8], bfr[4];
      #pragma unroll
      for (int m = 0; m < 8; ++m) af[m]  = ldsFrag(Ap, m * 16 + frow, fk);
      #pragma unroll
      for (int n = 0; n < 4; ++n) bfr[n] = ldsFrag(Bp, w * 64 + n * 16 + frow, fk);
      __builtin_amdgcn_s_setprio(1);
      #pragma unroll
      for (int m = 0; m < 8; ++m)
        #pragma unroll
        for (int n = 0; n < 4; ++n)
          acc[m][n] = __builtin_amdgcn_mfma_f32_16x16x32_bf16(af[m], bfr[n], acc[m][n], 0, 0, 0);
      __builtin_amdgcn_s_setprio(0);
    }
    if (more) asm volatile("s_waitcnt vmcnt(6)" ::: "memory");
    else      asm volatile("s_waitcnt vmcnt(0)" ::: "memory");
    __builtin_amdgcn_s_barrier();

    if (more){                       // stage unit u+3 (tile t+1, k-half 1) -> slot s (reads done)
      stage_half<2>(A,  tm0, K, (t + 1) * 64 + 32, As + s * 4096, w, lane);
      stage_half<4>(BT, tn0, K, (t + 1) * 64 + 32, Bs + s * 8192, w, lane);
    }
    {                                 // compute k1 from slot s1
      const u16* Ap = As + s1 * 4096;
      const u16* Bp = Bs + s1 * 8192;
      s16x8 af[8], bfr[4];
      #pragma unroll
      for (int m = 0; m < 8; ++m) af[m]  = ldsFrag(Ap, m * 16 + frow, fk);
      #pragma unroll
      for (int n = 0; n < 4; ++n) bfr[n] = ldsFrag(Bp, w * 64 + n * 16 + frow, fk);
      __builtin_amdgcn_s_setprio(1);
      #pragma unroll
      for (int m = 0; m < 8; ++m)
        #pragma unroll
        for (int n = 0; n < 4; ++n)
          acc[m][n] = __builtin_amdgcn_mfma_f32_16x16x32_bf16(af[m], bfr[n], acc[m][n], 0, 0, 0);
      __builtin_amdgcn_s_setprio(0);
    }
    if (more){
      asm volatile("s_waitcnt vmcnt(6)" ::: "memory");
      __builtin_amdgcn_s_barrier();
    }
    s = s2;
  }

  // epilogue: C layout col=lane&15, row=(lane>>4)*4+r
  #pragma unroll
  for (int m = 0; m < 8; ++m){
    const int row0 = tm0 + m * 16 + ((lane >> 4) << 2);
    #pragma unroll
    for (int n = 0; n < 4; ++n){
      const int col = tn0 + w * 64 + n * 16 + (lane & 15);
      #pragma unroll
      for (int r = 0; r < 4; ++r)
        cstore(C, (size_t)(row0 + r) * N + col, acc[m][n][r]);
    }
  }
}

// ---------------- swizzled LDS fragment reads (byte ^= (row&7)<<4) ----------------
__device__ __forceinline__ s16x8 ldsK(const u16* base, int row, int colB){
  int a = row * 256 + colB; a ^= (row & 7) << 4;
  return *(const s16x8*)((const char*)base + a);
}
__device__ __forceinline__ s16x8 ldsV(const u16* base, int row, int colB){
  int a = row * 128 + colB; a ^= (row & 7) << 4;
  return *(const s16x8*)((const char*)base + a);
}

// ---------------- flash attention: 512 blocks x 4 waves, paired 64-row tiles (unchanged, 77.5us) ----------------
__global__ __launch_bounds__(256, 2) void k_attn(const u16* __restrict__ qkv, const u16* __restrict__ vt,
                                                 u16* __restrict__ yb){
  __shared__ u16 Kt[2][64 * 128];   // [key][d], 2 x 16 KB, XOR-swizzled
  __shared__ u16 Vt[2][128 * 64];   // V^T [d][key], 2 x 16 KB, XOR-swizzled
  const int tid = threadIdx.x, lane = tid & 63, w = tid >> 6;   // w = 0..3
  const int ql = lane & 31, hi = lane >> 5;

  const int bx  = blockIdx.x;                 // 0..511
  const int xcd = bx & 7;
  const int b   = xcd >> 2;
  const int kvh = xcd & 3;
  const int slot = bx >> 3;                   // 0..63
  const int hl  = slot >> 4;                  // 0..3
  const int p   = (slot + 5 * hl) & 15;       // decorrelated pair index
  const int h   = kvh * 4 + hl;

  const int tile = (w < 2) ? (31 - p) : p;    // 64-row tiles
  const int tq0  = tile * 64 + (w & 1) * 32;
  const int myq  = tq0 + ql;
  const int nkb  = 32 - p;                    // key-blocks for the big tile

  const u16* kg  = qkv + (size_t)(b * T_SEQ) * QKVW + 2048 + kvh * 128;
  const u16* vgb = vt + ((size_t)(b * 512 + kvh * 128)) * T_SEQ;

  auto stageK = [&](int kbI, u16* dst){
    const int ks = kbI * 64;
    #pragma unroll
    for (int cc = 0; cc < 4; ++cc){
      const int call = w * 4 + cc;             // 0..15
      const int o = call * 64 + lane;          // 16 chunks/row
      const int f = o ^ ((o >> 4) & 7);
      g2lds16(kg + (size_t)(ks + (o >> 4)) * QKVW + (f & 15) * 8, dst + call * 512);
    }
  };
  auto stageV = [&](int kbI, u16* dst){
    const int ks = kbI * 64;
    #pragma unroll
    for (int cc = 0; cc < 4; ++cc){
      const int call = w * 4 + cc;
      const int o = call * 64 + lane;          // 8 chunks/row, row = d
      const int f = o ^ ((o >> 3) & 7);
      g2lds16(vgb + (size_t)(o >> 3) * T_SEQ + ks + (f & 7) * 8, dst + call * 512);
    }
  };

  // prologue: stage K(0),V(0) into buffers [0]
  stageK(0, Kt[0]);
  stageV(0, Vt[0]);

  const u16* qrow = qkv + ((size_t)(b * T_SEQ + myq)) * QKVW + h * HD + hi * 8;
  s16x8 qf[8];
  #pragma unroll
  for (int kc = 0; kc < 8; ++kc) qf[kc] = *(const s16x8*)(qrow + kc * 16);

  f32x16 O[4] = {};
  float mloc = -1e30f, lloc = 0.0f;

  asm volatile("s_waitcnt vmcnt(0)" ::: "memory");
  __builtin_amdgcn_s_barrier();

  for (int kbI = 0; kbI < nkb; ++kbI){
    const int ks  = kbI * 64;
    const int cur = kbI & 1;

    // issue next tile's staging into the other buffers
    if (kbI + 1 < nkb){
      stageV(kbI + 1, Vt[cur ^ 1]);
      stageK(kbI + 1, Kt[cur ^ 1]);
    }

    if (ks <= tq0 + 31){
      const u16* Kc = Kt[cur];
      const u16* Vc = Vt[cur];
      const bool doN1 = (ks + 32 <= tq0 + 31);
      f32x16 S0 = {}, S1 = {};
      __builtin_amdgcn_s_setprio(1);
      #pragma unroll
      for (int kc = 0; kc < 8; ++kc)
        S0 = __builtin_amdgcn_mfma_f32_32x32x16_bf16(ldsK(Kc, ql, kc*32 + hi*16), qf[kc], S0, 0, 0, 0);
      if (doN1){
        #pragma unroll
        for (int kc = 0; kc < 8; ++kc)
          S1 = __builtin_amdgcn_mfma_f32_32x32x16_bf16(ldsK(Kc, 32 + ql, kc*32 + hi*16), qf[kc], S1, 0, 0, 0);
      }
      __builtin_amdgcn_s_setprio(0);
      // causal mask; key(r) = ks + ntile*32 + (r&3) + 8*(r>>2) + 4*hi
      if (ks + 31 > tq0){
        #pragma unroll
        for (int r = 0; r < 16; ++r)
          if (ks + (r&3) + 8*(r>>2) + 4*hi > myq) S0[r] = -1e30f;
      }
      if (doN1 && (ks + 63 > tq0)){
        #pragma unroll
        for (int r = 0; r < 16; ++r)
          if (ks + 32 + (r&3) + 8*(r>>2) + 4*hi > myq) S1[r] = -1e30f;
      }
      float mr = -1e30f;
      #pragma unroll
      for (int r = 0; r < 16; ++r) mr = fmaxf(mr, S0[r]);
      if (doN1){
        #pragma unroll
        for (int r = 0; r < 16; ++r) mr = fmaxf(mr, S1[r]);
      }
      mr = fmaxf(mr, __shfl_xor(mr, 32));
      if (!__all(mr <= mloc + 8.0f)){       // defer-max (T13)
        const float mn = fmaxf(mloc, mr);
        const float a  = __expf(mloc - mn);
        mloc = mn; lloc *= a;
        #pragma unroll
        for (int dt = 0; dt < 4; ++dt)
          #pragma unroll
          for (int r = 0; r < 16; ++r) O[dt][r] *= a;
      }
      float rs = 0.0f;
      #pragma unroll
      for (int r = 0; r < 16; ++r){ S0[r] = __expf(S0[r] - mloc); rs += S0[r]; }
      if (doN1){
        #pragma unroll
        for (int r = 0; r < 16; ++r){ S1[r] = __expf(S1[r] - mloc); rs += S1[r]; }
      }
      rs += __shfl_xor(rs, 32);
      lloc += rs;
      // pack P^T -> PV B-frags
      u32 bw[16];
      {
        u32 pk[8], pp[8];
        #pragma unroll
        for (int j = 0; j < 8; ++j) pk[j] = pkbf(S0[2*j], S0[2*j+1]);
        #pragma unroll
        for (int j = 0; j < 8; ++j) pp[j] = (u32)__shfl_xor((int)pk[j], 32);
        bw[0] = hi ? pp[2] : pk[0];  bw[1] = hi ? pp[3] : pk[1];
        bw[2] = hi ? pk[2] : pp[0];  bw[3] = hi ? pk[3] : pp[1];
        bw[4] = hi ? pp[6] : pk[4];  bw[5] = hi ? pp[7] : pk[5];
        bw[6] = hi ? pk[6] : pp[4];  bw[7] = hi ? pk[7] : pp[5];
      }
      int nkc = 2;
      if (doN1){
        u32 pk[8], pp[8];
        #pragma unroll
        for (int j = 0; j < 8; ++j) pk[j] = pkbf(S1[2*j], S1[2*j+1]);
        #pragma unroll
        for (int j = 0; j < 8; ++j) pp[j] = (u32)__shfl_xor((int)pk[j], 32);
        bw[8]  = hi ? pp[2] : pk[0];  bw[9]  = hi ? pp[3] : pk[1];
        bw[10] = hi ? pk[2] : pp[0];  bw[11] = hi ? pk[3] : pp[1];
        bw[12] = hi ? pp[6] : pk[4];  bw[13] = hi ? pp[7] : pk[5];
        bw[14] = hi ? pk[6] : pp[4];  bw[15] = hi ? pk[7] : pp[5];
        nkc = 4;
      }
      // PV directly from Vt[cur]
      __builtin_amdgcn_s_setprio(1);
      #pragma unroll
      for (int kc = 0; kc < 4; ++kc){
        if (kc < nkc){
          union { u32 u[4]; s16x8 v; } pb;
          pb.u[0] = bw[kc*4+0]; pb.u[1] = bw[kc*4+1]; pb.u[2] = bw[kc*4+2]; pb.u[3] = bw[kc*4+3];
          #pragma unroll
          for (int dt = 0; dt < 4; ++dt)
            O[dt] = __builtin_amdgcn_mfma_f32_32x32x16_bf16(ldsV(Vc, dt*32 + ql, kc*32 + hi*16), pb.v, O[dt], 0, 0, 0);
        }
      }
      __builtin_amdgcn_s_setprio(0);
    }

    // single sync point: next buffers landed; all waves done with current buffers
    asm volatile("s_waitcnt vmcnt(0)" ::: "memory");
    __builtin_amdgcn_s_barrier();
  }

  // epilogue: normalize, pack, store
  const float linv = 1.0f / lloc;
  u16* yr = yb + ((size_t)(b * T_SEQ + myq)) * NE + h * HD;
  #pragma unroll
  for (int dt = 0; dt < 4; ++dt){
    #pragma unroll
    for (int mq = 0; mq < 4; ++mq){
      uint2 s;
      s.x = pkbf(O[dt][4*mq+0] * linv, O[dt][4*mq+1] * linv);
      s.y = pkbf(O[dt][4*mq+2] * linv, O[dt][4*mq+3] * linv);
      *(uint2*)(yr + dt*32 + 8*mq + 4*hi) = s;
    }
  }
}

// ---------------- launch ----------------
extern "C" void kernel_launch(void* const* d_in, const int* in_sizes, int n_in,
                              void* d_out, int out_size, void* d_ws, size_t ws_size,
                              hipStream_t stream){
  const float* x  = (const float*)d_in[0];
  const float* wq = (const float*)d_in[1];
  const float* wk = (const float*)d_in[2];
  const float* wv = (const float*)d_in[3];
  const float* wo = (const float*)d_in[4];
  float* out = (float*)d_out;

  char* w = (char*)d_ws;
  u16* xb    = (u16*)w;  w += (size_t)4096 * 2048 * 2;   // 16 MB
  u16* wqkvT = (u16*)w;  w += (size_t)3072 * 2048 * 2;   // 12 MB
  u16* woT   = (u16*)w;  w += (size_t)2048 * 2048 * 2;   //  8 MB
  u16* qkv   = (u16*)w;  w += (size_t)4096 * 3072 * 2;   // 24 MB
  u16* vtb   = (u16*)w;  w += (size_t)4096 * 512  * 2;   //  4 MB
  u16* yb    = (u16*)w;  w += (size_t)4096 * 2048 * 2;   // 16 MB
  float* cosT = (float*)w; w += (size_t)2048 * 64 * 4;   // 0.5 MB
  float* sinT = (float*)w; w += (size_t)2048 * 64 * 4;   // 0.5 MB

  const float SCALE = 0.08838834764831845f;  // 1/sqrt(128), folded into q

  // 1) fused prep
  k_prep<<<PREP_NBLK, 256, 0, stream>>>(x, wq, wk, wv, wo, xb, wqkvT, woT, cosT, sinT);

  // 2) fused QKV projection: [4096][3072]  (384 blocks: 32 mtiles x 12 ntiles of 256)
  k_gemm<u16><<<384, 256, 0, stream>>>(xb, wqkvT, qkv, 4096, QKVW, 2048);

  // 3) fused post: RoPE q/k + V transpose
  k_post<<<POST_NBLK, 256, 0, stream>>>(qkv, vtb, cosT, sinT, SCALE);

  // 4) causal flash attention (512 x 4-wave paired blocks, 2 blocks/CU)
  k_attn<<<512, 256, 0, stream>>>(qkv, vtb, yb);

  // 5) output projection -> fp32  (256 blocks: 32 mtiles x 8 ntiles of 256)
  k_gemm<float><<<256, 256, 0, stream>>>(yb, woT, out, 4096, 2048, 2048);
}

// Round 14
// 222.531 us; speedup vs baseline: 1.0825x; 1.0825x over previous
//
#include <hip/hip_runtime.h>
#include <stdint.h>

typedef unsigned short u16;
typedef unsigned int   u32;
typedef float f32x4  __attribute__((ext_vector_type(4)));
typedef float f32x16 __attribute__((ext_vector_type(16)));
typedef short s16x8  __attribute__((ext_vector_type(8)));

#define T_SEQ 2048
#define NE    2048
#define NH    16
#define NKV   4
#define HD    128
#define QKVW  3072   // fused qkv row width

__device__ __forceinline__ u16 f2bf(float f){
  u32 u = __float_as_uint(f);
  u32 r = u + 0x7FFFu + ((u >> 16) & 1u);   // RNE
  return (u16)(r >> 16);
}
__device__ __forceinline__ float bf2f(u16 h){ return __uint_as_float(((u32)h) << 16); }

// packed f32x2 -> bf16x2 (RNE), no builtin on gfx950
__device__ __forceinline__ u32 pkbf(float a, float b){
  u32 r; asm("v_cvt_pk_bf16_f32 %0, %1, %2" : "=v"(r) : "v"(a), "v"(b)); return r;
}

typedef __attribute__((address_space(3))) u32 lds_u32;
typedef __attribute__((address_space(1))) u32 glb_u32;
__device__ __forceinline__ void g2lds16(const void* g, void* l){
  __builtin_amdgcn_global_load_lds((const glb_u32*)g, (lds_u32*)l, 16, 0, 0);
}

// ================= fused prep: x cvt + 4 weight transposes + rope tables =================
#define PREP_NBLK 18944
__global__ __launch_bounds__(256) void k_prep(const float* __restrict__ x,
                                              const float* __restrict__ wq, const float* __restrict__ wk,
                                              const float* __restrict__ wv, const float* __restrict__ wo,
                                              u16* __restrict__ xb, u16* __restrict__ wqkvT, u16* __restrict__ woT,
                                              float* __restrict__ cosT, float* __restrict__ sinT){
  __shared__ float t[32][33];
  const int blk = blockIdx.x, tid = threadIdx.x;
  if (blk < 8192){                                   // ---- x fp32 -> bf16
    int i = (blk * 256 + tid) * 4;
    float4 v = *(const float4*)(x + i);
    ushort4 o; o.x = f2bf(v.x); o.y = f2bf(v.y); o.z = f2bf(v.z); o.w = f2bf(v.w);
    *(ushort4*)(xb + i) = o;
    return;
  }
  if (blk >= 18432){                                 // ---- rope tables [T][64]
    int i = (blk - 18432) * 256 + tid;               // t*64 + j
    int tt = i >> 6, j = i & 63;
    float inv = expf(-(float)j * (11.512925464970229f / 64.0f));  // ln(1e5)
    float f = (float)tt * inv;
    cosT[i] = cosf(f);
    sinT[i] = sinf(f);
    return;
  }
  // ---- weight transpose+convert W[R=2048][C] -> WT[C][2048]
  const float* in; u16* out; int C; int tt;
  if      (blk < 12288){ in = wq; out = wqkvT;                     C = 2048; tt = blk - 8192;  }
  else if (blk < 13312){ in = wk; out = wqkvT + (size_t)2048*2048; C = 512;  tt = blk - 12288; }
  else if (blk < 14336){ in = wv; out = wqkvT + (size_t)2560*2048; C = 512;  tt = blk - 13312; }
  else                 { in = wo; out = woT;                       C = 2048; tt = blk - 14336; }
  const int r0 = (tt & 63) * 32, c0 = (tt >> 6) * 32;
  const int tx = tid & 31, ty = tid >> 5;
  #pragma unroll
  for (int i = 0; i < 4; ++i) t[ty + i*8][tx] = in[(size_t)(r0 + ty + i*8) * C + c0 + tx];
  __syncthreads();
  #pragma unroll
  for (int i = 0; i < 4; ++i) out[(size_t)(c0 + ty + i*8) * 2048 + r0 + tx] = f2bf(t[tx][ty + i*8]);
}

// ================= fused post: rope(q) + rope(k) + V transpose =================
#define POST_NBLK 22528
__global__ __launch_bounds__(256) void k_post(u16* __restrict__ qkv, u16* __restrict__ vtb,
                                              const float* __restrict__ cosT, const float* __restrict__ sinT,
                                              float qscale){
  __shared__ u16 tsh[32][33];
  const int blk = blockIdx.x, tid = threadIdx.x;
  if (blk < 20480){                                  // ---- RoPE + RMS-norm in place
    u16* base; int log2h; float scale; int rh;
    if (blk < 16384){ base = qkv;        log2h = 4; scale = qscale; rh = blk * 4 + (tid >> 6); }
    else            { base = qkv + 2048; log2h = 2; scale = 1.0f;   rh = (blk - 16384) * 4 + (tid >> 6); }
    const int lane = tid & 63;
    const int row = rh >> log2h;                     // b*T + t
    const int h   = rh & ((1 << log2h) - 1);
    const int t   = row & (T_SEQ - 1);
    u16* p = base + (size_t)row * QKVW + h * HD;
    float x1 = bf2f(p[lane]), x2 = bf2f(p[lane + 64]);
    float c = cosT[t * 64 + lane], s = sinT[t * 64 + lane];
    float y1 = x1 * c + x2 * s;
    float y2 = x2 * c - x1 * s;
    float sq = y1 * y1 + y2 * y2;
    #pragma unroll
    for (int off = 32; off; off >>= 1) sq += __shfl_xor(sq, off);
    float sc = rsqrtf(sq * (1.0f / 128.0f) + 1e-6f) * scale;
    p[lane]      = f2bf(y1 * sc);
    p[lane + 64] = f2bf(y2 * sc);
    return;
  }
  // ---- V transpose: per b, qkv[t][2560+c] -> vtb[b][c][t]
  const int tt = blk - 20480;
  const int r0 = (tt & 63) * 32, c0 = ((tt >> 6) & 15) * 32, b = tt >> 10;
  const u16* ib = qkv + (size_t)b * T_SEQ * QKVW + 2560;
  u16*       ob = vtb + (size_t)b * 512 * T_SEQ;
  const int tx = tid & 31, ty = tid >> 5;
  #pragma unroll
  for (int i = 0; i < 4; ++i) tsh[ty + i*8][tx] = ib[(size_t)(r0 + ty + i*8) * QKVW + c0 + tx];
  __syncthreads();
  #pragma unroll
  for (int i = 0; i < 4; ++i) ob[(size_t)(c0 + ty + i*8) * T_SEQ + r0 + tx] = tsh[tx][ty + i*8];
}

// ================= GEMM: 128x128 tile, BK=64 as 2 half-units, 3-slot LDS ring, counted vmcnt =================
// (validated R9/R12: qkv ~59us, out ~39us, ~870 TF)
__device__ __forceinline__ void cstore(u16* C, size_t i, float v){ C[i] = f2bf(v); }
__device__ __forceinline__ void cstore(float* C, size_t i, float v){ C[i] = v; }

__device__ __forceinline__ void stage_half(const u16* __restrict__ G, int row0, int K, int k0,
                                           u16* lds, int w, int lane){
  #pragma unroll
  for (int call = 0; call < 2; ++call){
    const int o  = call * 256 + w * 64 + lane;   // chunk 0..511
    const int rp = o >> 3, sl = o & 7;
    const int lg = sl ^ (rp & 7);                // logical (h,kc)
    const int row = rp * 2 + (lg >> 2);
    const int kc  = lg & 3;
    g2lds16(G + (size_t)(row0 + row) * K + k0 + kc * 8, lds + (size_t)(call * 256 + w * 64) * 8);
  }
}

__device__ __forceinline__ s16x8 ldsFrag(const u16* slotBase, int row, int kchunk){
  const int byte = (row >> 1) * 128 + (((((row & 1) << 2) | kchunk) ^ ((row >> 1) & 7)) << 4);
  return *(const s16x8*)((const char*)slotBase + byte);
}

template <typename CT>
__global__ __launch_bounds__(256, 3) void k_gemm(const u16* __restrict__ A, const u16* __restrict__ BT,
                                                 CT* __restrict__ C, int M, int N, int K, int NPX){
  __shared__ u16 As[3 * 4096];   // 3 slots x 8KB
  __shared__ u16 Bs[3 * 4096];
  const int tid  = threadIdx.x;
  const int lane = tid & 63;
  const int w    = tid >> 6;
  const int wr = w >> 1, wc = w & 1;
  const int bid = blockIdx.x;
  const int xcd = bid & 7, ii = bid >> 3;
  const int ntile = xcd * NPX + ii % NPX;
  const int mtile = ii / NPX;
  const int tm0 = mtile * 128, tn0 = ntile * 128;
  const int frow = lane & 15, fk = lane >> 4;

  f32x4 acc[4][4] = {};
  const int nkt = K >> 6;

  stage_half(A,  tm0, K, 0,  As,        w, lane);
  stage_half(BT, tn0, K, 0,  Bs,        w, lane);
  stage_half(A,  tm0, K, 32, As + 4096, w, lane);
  stage_half(BT, tn0, K, 32, Bs + 4096, w, lane);
  asm volatile("s_waitcnt vmcnt(4)" ::: "memory");
  __builtin_amdgcn_s_barrier();

  int s = 0;
  #pragma unroll 1
  for (int t = 0; t < nkt; ++t){
    const int s1 = (s + 1 > 2) ? 0 : s + 1;
    const int s2 = (s + 2 > 2) ? s - 1 : s + 2;
    const bool more = (t + 1 < nkt);

    if (more){
      stage_half(A,  tm0, K, (t + 1) * 64,  As + s2 * 4096, w, lane);
      stage_half(BT, tn0, K, (t + 1) * 64,  Bs + s2 * 4096, w, lane);
    }
    {
      const u16* Ap = As + s * 4096;
      const u16* Bp = Bs + s * 4096;
      s16x8 af[4], bfr[4];
      #pragma unroll
      for (int m = 0; m < 4; ++m) af[m]  = ldsFrag(Ap, wr * 64 + m * 16 + frow, fk);
      #pragma unroll
      for (int n = 0; n < 4; ++n) bfr[n] = ldsFrag(Bp, wc * 64 + n * 16 + frow, fk);
      __builtin_amdgcn_s_setprio(1);
      #pragma unroll
      for (int m = 0; m < 4; ++m)
        #pragma unroll
        for (int n = 0; n < 4; ++n)
          acc[m][n] = __builtin_amdgcn_mfma_f32_16x16x32_bf16(af[m], bfr[n], acc[m][n], 0, 0, 0);
      __builtin_amdgcn_s_setprio(0);
    }
    if (more) asm volatile("s_waitcnt vmcnt(4)" ::: "memory");
    else      asm volatile("s_waitcnt vmcnt(0)" ::: "memory");
    __builtin_amdgcn_s_barrier();

    if (more){
      stage_half(A,  tm0, K, (t + 1) * 64 + 32, As + s * 4096, w, lane);
      stage_half(BT, tn0, K, (t + 1) * 64 + 32, Bs + s * 4096, w, lane);
    }
    {
      const u16* Ap = As + s1 * 4096;
      const u16* Bp = Bs + s1 * 4096;
      s16x8 af[4], bfr[4];
      #pragma unroll
      for (int m = 0; m < 4; ++m) af[m]  = ldsFrag(Ap, wr * 64 + m * 16 + frow, fk);
      #pragma unroll
      for (int n = 0; n < 4; ++n) bfr[n] = ldsFrag(Bp, wc * 64 + n * 16 + frow, fk);
      __builtin_amdgcn_s_setprio(1);
      #pragma unroll
      for (int m = 0; m < 4; ++m)
        #pragma unroll
        for (int n = 0; n < 4; ++n)
          acc[m][n] = __builtin_amdgcn_mfma_f32_16x16x32_bf16(af[m], bfr[n], acc[m][n], 0, 0, 0);
      __builtin_amdgcn_s_setprio(0);
    }
    if (more){
      asm volatile("s_waitcnt vmcnt(4)" ::: "memory");
      __builtin_amdgcn_s_barrier();
    }
    s = s2;
  }

  #pragma unroll
  for (int m = 0; m < 4; ++m){
    const int row0 = tm0 + wr * 64 + m * 16 + ((lane >> 4) << 2);
    #pragma unroll
    for (int n = 0; n < 4; ++n){
      const int col = tn0 + wc * 64 + n * 16 + (lane & 15);
      #pragma unroll
      for (int r = 0; r < 4; ++r)
        cstore(C, (size_t)(row0 + r) * N + col, acc[m][n][r]);
    }
  }
}

// ---------------- swizzled LDS fragment reads (byte ^= (row&7)<<4) ----------------
__device__ __forceinline__ s16x8 ldsK(const u16* base, int row, int colB){
  int a = row * 256 + colB; a ^= (row & 7) << 4;
  return *(const s16x8*)((const char*)base + a);
}
__device__ __forceinline__ s16x8 ldsV(const u16* base, int row, int colB){
  int a = row * 128 + colB; a ^= (row & 7) << 4;
  return *(const s16x8*)((const char*)base + a);
}

// ---------------- flash attention: 512 blocks x 4 waves, paired 64-row tiles, 2 blocks/CU ----------------
// (validated R10/R12: 77.5us)
__global__ __launch_bounds__(256, 2) void k_attn(const u16* __restrict__ qkv, const u16* __restrict__ vt,
                                                 u16* __restrict__ yb){
  __shared__ u16 Kt[2][64 * 128];   // [key][d], 2 x 16 KB, XOR-swizzled
  __shared__ u16 Vt[2][128 * 64];   // V^T [d][key], 2 x 16 KB, XOR-swizzled
  const int tid = threadIdx.x, lane = tid & 63, w = tid >> 6;   // w = 0..3
  const int ql = lane & 31, hi = lane >> 5;

  const int bx  = blockIdx.x;                 // 0..511
  const int xcd = bx & 7;
  const int b   = xcd >> 2;
  const int kvh = xcd & 3;
  const int slot = bx >> 3;                   // 0..63
  const int hl  = slot >> 4;                  // 0..3
  const int p   = (slot + 5 * hl) & 15;       // decorrelated pair index
  const int h   = kvh * 4 + hl;

  const int tile = (w < 2) ? (31 - p) : p;    // 64-row tiles
  const int tq0  = tile * 64 + (w & 1) * 32;
  const int myq  = tq0 + ql;
  const int nkb  = 32 - p;                    // key-blocks for the big tile

  const u16* kg  = qkv + (size_t)(b * T_SEQ) * QKVW + 2048 + kvh * 128;
  const u16* vgb = vt + ((size_t)(b * 512 + kvh * 128)) * T_SEQ;

  auto stageK = [&](int kbI, u16* dst){
    const int ks = kbI * 64;
    #pragma unroll
    for (int cc = 0; cc < 4; ++cc){
      const int call = w * 4 + cc;             // 0..15
      const int o = call * 64 + lane;          // 16 chunks/row
      const int f = o ^ ((o >> 4) & 7);
      g2lds16(kg + (size_t)(ks + (o >> 4)) * QKVW + (f & 15) * 8, dst + call * 512);
    }
  };
  auto stageV = [&](int kbI, u16* dst){
    const int ks = kbI * 64;
    #pragma unroll
    for (int cc = 0; cc < 4; ++cc){
      const int call = w * 4 + cc;
      const int o = call * 64 + lane;          // 8 chunks/row, row = d
      const int f = o ^ ((o >> 3) & 7);
      g2lds16(vgb + (size_t)(o >> 3) * T_SEQ + ks + (f & 7) * 8, dst + call * 512);
    }
  };

  // prologue: stage K(0),V(0) into buffers [0]
  stageK(0, Kt[0]);
  stageV(0, Vt[0]);

  const u16* qrow = qkv + ((size_t)(b * T_SEQ + myq)) * QKVW + h * HD + hi * 8;
  s16x8 qf[8];
  #pragma unroll
  for (int kc = 0; kc < 8; ++kc) qf[kc] = *(const s16x8*)(qrow + kc * 16);

  f32x16 O[4] = {};
  float mloc = -1e30f, lloc = 0.0f;

  asm volatile("s_waitcnt vmcnt(0)" ::: "memory");
  __builtin_amdgcn_s_barrier();

  for (int kbI = 0; kbI < nkb; ++kbI){
    const int ks  = kbI * 64;
    const int cur = kbI & 1;

    // issue next tile's staging into the other buffers
    if (kbI + 1 < nkb){
      stageV(kbI + 1, Vt[cur ^ 1]);
      stageK(kbI + 1, Kt[cur ^ 1]);
    }

    if (ks <= tq0 + 31){
      const u16* Kc = Kt[cur];
      const u16* Vc = Vt[cur];
      const bool doN1 = (ks + 32 <= tq0 + 31);
      f32x16 S0 = {}, S1 = {};
      __builtin_amdgcn_s_setprio(1);
      #pragma unroll
      for (int kc = 0; kc < 8; ++kc)
        S0 = __builtin_amdgcn_mfma_f32_32x32x16_bf16(ldsK(Kc, ql, kc*32 + hi*16), qf[kc], S0, 0, 0, 0);
      if (doN1){
        #pragma unroll
        for (int kc = 0; kc < 8; ++kc)
          S1 = __builtin_amdgcn_mfma_f32_32x32x16_bf16(ldsK(Kc, 32 + ql, kc*32 + hi*16), qf[kc], S1, 0, 0, 0);
      }
      __builtin_amdgcn_s_setprio(0);
      // causal mask; key(r) = ks + ntile*32 + (r&3) + 8*(r>>2) + 4*hi
      if (ks + 31 > tq0){
        #pragma unroll
        for (int r = 0; r < 16; ++r)
          if (ks + (r&3) + 8*(r>>2) + 4*hi > myq) S0[r] = -1e30f;
      }
      if (doN1 && (ks + 63 > tq0)){
        #pragma unroll
        for (int r = 0; r < 16; ++r)
          if (ks + 32 + (r&3) + 8*(r>>2) + 4*hi > myq) S1[r] = -1e30f;
      }
      float mr = -1e30f;
      #pragma unroll
      for (int r = 0; r < 16; ++r) mr = fmaxf(mr, S0[r]);
      if (doN1){
        #pragma unroll
        for (int r = 0; r < 16; ++r) mr = fmaxf(mr, S1[r]);
      }
      mr = fmaxf(mr, __shfl_xor(mr, 32));
      if (!__all(mr <= mloc + 8.0f)){       // defer-max (T13)
        const float mn = fmaxf(mloc, mr);
        const float a  = __expf(mloc - mn);
        mloc = mn; lloc *= a;
        #pragma unroll
        for (int dt = 0; dt < 4; ++dt)
          #pragma unroll
          for (int r = 0; r < 16; ++r) O[dt][r] *= a;
      }
      float rs = 0.0f;
      #pragma unroll
      for (int r = 0; r < 16; ++r){ S0[r] = __expf(S0[r] - mloc); rs += S0[r]; }
      if (doN1){
        #pragma unroll
        for (int r = 0; r < 16; ++r){ S1[r] = __expf(S1[r] - mloc); rs += S1[r]; }
      }
      rs += __shfl_xor(rs, 32);
      lloc += rs;
      // pack P^T -> PV B-frags
      u32 bw[16];
      {
        u32 pk[8], pp[8];
        #pragma unroll
        for (int j = 0; j < 8; ++j) pk[j] = pkbf(S0[2*j], S0[2*j+1]);
        #pragma unroll
        for (int j = 0; j < 8; ++j) pp[j] = (u32)__shfl_xor((int)pk[j], 32);
        bw[0] = hi ? pp[2] : pk[0];  bw[1] = hi ? pp[3] : pk[1];
        bw[2] = hi ? pk[2] : pp[0];  bw[3] = hi ? pk[3] : pp[1];
        bw[4] = hi ? pp[6] : pk[4];  bw[5] = hi ? pp[7] : pk[5];
        bw[6] = hi ? pk[6] : pp[4];  bw[7] = hi ? pk[7] : pp[5];
      }
      int nkc = 2;
      if (doN1){
        u32 pk[8], pp[8];
        #pragma unroll
        for (int j = 0; j < 8; ++j) pk[j] = pkbf(S1[2*j], S1[2*j+1]);
        #pragma unroll
        for (int j = 0; j < 8; ++j) pp[j] = (u32)__shfl_xor((int)pk[j], 32);
        bw[8]  = hi ? pp[2] : pk[0];  bw[9]  = hi ? pp[3] : pk[1];
        bw[10] = hi ? pk[2] : pp[0];  bw[11] = hi ? pk[3] : pp[1];
        bw[12] = hi ? pp[6] : pk[4];  bw[13] = hi ? pp[7] : pk[5];
        bw[14] = hi ? pk[6] : pp[4];  bw[15] = hi ? pk[7] : pp[5];
        nkc = 4;
      }
      // PV directly from Vt[cur]
      __builtin_amdgcn_s_setprio(1);
      #pragma unroll
      for (int kc = 0; kc < 4; ++kc){
        if (kc < nkc){
          union { u32 u[4]; s16x8 v; } pb;
          pb.u[0] = bw[kc*4+0]; pb.u[1] = bw[kc*4+1]; pb.u[2] = bw[kc*4+2]; pb.u[3] = bw[kc*4+3];
          #pragma unroll
          for (int dt = 0; dt < 4; ++dt)
            O[dt] = __builtin_amdgcn_mfma_f32_32x32x16_bf16(ldsV(Vc, dt*32 + ql, kc*32 + hi*16), pb.v, O[dt], 0, 0, 0);
        }
      }
      __builtin_amdgcn_s_setprio(0);
    }

    // single sync point: next buffers landed; all waves done with current buffers
    asm volatile("s_waitcnt vmcnt(0)" ::: "memory");
    __builtin_amdgcn_s_barrier();
  }

  // epilogue: normalize, pack, store
  const float linv = 1.0f / lloc;
  u16* yr = yb + ((size_t)(b * T_SEQ + myq)) * NE + h * HD;
  #pragma unroll
  for (int dt = 0; dt < 4; ++dt){
    #pragma unroll
    for (int mq = 0; mq < 4; ++mq){
      uint2 s;
      s.x = pkbf(O[dt][4*mq+0] * linv, O[dt][4*mq+1] * linv);
      s.y = pkbf(O[dt][4*mq+2] * linv, O[dt][4*mq+3] * linv);
      *(uint2*)(yr + dt*32 + 8*mq + 4*hi) = s;
    }
  }
}

// ---------------- launch ----------------
extern "C" void kernel_launch(void* const* d_in, const int* in_sizes, int n_in,
                              void* d_out, int out_size, void* d_ws, size_t ws_size,
                              hipStream_t stream){
  const float* x  = (const float*)d_in[0];
  const float* wq = (const float*)d_in[1];
  const float* wk = (const float*)d_in[2];
  const float* wv = (const float*)d_in[3];
  const float* wo = (const float*)d_in[4];
  float* out = (float*)d_out;

  char* w = (char*)d_ws;
  u16* xb    = (u16*)w;  w += (size_t)4096 * 2048 * 2;   // 16 MB
  u16* wqkvT = (u16*)w;  w += (size_t)3072 * 2048 * 2;   // 12 MB
  u16* woT   = (u16*)w;  w += (size_t)2048 * 2048 * 2;   //  8 MB
  u16* qkv   = (u16*)w;  w += (size_t)4096 * 3072 * 2;   // 24 MB
  u16* vtb   = (u16*)w;  w += (size_t)4096 * 512  * 2;   //  4 MB
  u16* yb    = (u16*)w;  w += (size_t)4096 * 2048 * 2;   // 16 MB
  float* cosT = (float*)w; w += (size_t)2048 * 64 * 4;   // 0.5 MB
  float* sinT = (float*)w; w += (size_t)2048 * 64 * 4;   // 0.5 MB

  const float SCALE = 0.08838834764831845f;  // 1/sqrt(128), folded into q

  // 1) fused prep
  k_prep<<<PREP_NBLK, 256, 0, stream>>>(x, wq, wk, wv, wo, xb, wqkvT, woT, cosT, sinT);

  // 2) fused QKV projection: [4096][3072]  (768 blocks, NPX=3, 3 blocks/CU uniform)
  k_gemm<u16><<<768, 256, 0, stream>>>(xb, wqkvT, qkv, 4096, QKVW, 2048, 3);

  // 3) fused post: RoPE q/k + V transpose
  k_post<<<POST_NBLK, 256, 0, stream>>>(qkv, vtb, cosT, sinT, SCALE);

  // 4) causal flash attention (512 x 4-wave paired blocks, 2 blocks/CU)
  k_attn<<<512, 256, 0, stream>>>(qkv, vtb, yb);

  // 5) output projection -> fp32  (512 blocks, NPX=2, 2 blocks/CU uniform)
  k_gemm<float><<<512, 256, 0, stream>>>(yb, woT, out, 4096, 2048, 2048, 2);
}

// Round 15
// 216.513 us; speedup vs baseline: 1.1126x; 1.0278x over previous
//
#include <hip/hip_runtime.h>
#include <stdint.h>

typedef unsigned short u16;
typedef unsigned int   u32;
typedef float f32x4  __attribute__((ext_vector_type(4)));
typedef float f32x16 __attribute__((ext_vector_type(16)));
typedef short s16x8  __attribute__((ext_vector_type(8)));

#define T_SEQ 2048
#define NE    2048
#define NH    16
#define NKV   4
#define HD    128
#define QKVW  3072   // fused qkv row width

__device__ __forceinline__ u16 f2bf(float f){
  u32 u = __float_as_uint(f);
  u32 r = u + 0x7FFFu + ((u >> 16) & 1u);   // RNE
  return (u16)(r >> 16);
}
__device__ __forceinline__ float bf2f(u16 h){ return __uint_as_float(((u32)h) << 16); }

// packed f32x2 -> bf16x2 (RNE), no builtin on gfx950
__device__ __forceinline__ u32 pkbf(float a, float b){
  u32 r; asm("v_cvt_pk_bf16_f32 %0, %1, %2" : "=v"(r) : "v"(a), "v"(b)); return r;
}

typedef __attribute__((address_space(3))) u32 lds_u32;
typedef __attribute__((address_space(1))) u32 glb_u32;
__device__ __forceinline__ void g2lds16(const void* g, void* l){
  __builtin_amdgcn_global_load_lds((const glb_u32*)g, (lds_u32*)l, 16, 0, 0);
}

// ================= fused prep: x cvt + 4 weight transposes + rope tables =================
// ranges: [0,4096) x-cvt (8 elems/thr) | [4096,5120) wq | [5120,5376) wk | [5376,5632) wv
//         [5632,6656) wo | [6656,7168) tables.  Transposes: 64x64 tiles, (64,4) threads,
//         128B-contiguous u16 writes per wave-row.
#define PREP_NBLK 7168
__global__ __launch_bounds__(256) void k_prep(const float* __restrict__ x,
                                              const float* __restrict__ wq, const float* __restrict__ wk,
                                              const float* __restrict__ wv, const float* __restrict__ wo,
                                              u16* __restrict__ xb, u16* __restrict__ wqkvT, u16* __restrict__ woT,
                                              float* __restrict__ cosT, float* __restrict__ sinT){
  __shared__ float t[64][65];   // bank-clean: word (65*tx + c) % 32 = (tx + c) % 32
  const int blk = blockIdx.x, tid = threadIdx.x;
  if (blk < 4096){                                   // ---- x fp32 -> bf16, 8/thread
    const int i = (blk * 256 + tid) * 8;
    float4 v0 = *(const float4*)(x + i);
    float4 v1 = *(const float4*)(x + i + 4);
    uint4 o;
    o.x = ((u32)f2bf(v0.y) << 16) | f2bf(v0.x);
    o.y = ((u32)f2bf(v0.w) << 16) | f2bf(v0.z);
    o.z = ((u32)f2bf(v1.y) << 16) | f2bf(v1.x);
    o.w = ((u32)f2bf(v1.w) << 16) | f2bf(v1.z);
    *(uint4*)(xb + i) = o;
    return;
  }
  if (blk >= 6656){                                  // ---- rope tables [T][64]
    int i = (blk - 6656) * 256 + tid;                // t*64 + j
    int tt = i >> 6, j = i & 63;
    float inv = expf(-(float)j * (11.512925464970229f / 64.0f));  // ln(1e5)
    float f = (float)tt * inv;
    cosT[i] = cosf(f);
    sinT[i] = sinf(f);
    return;
  }
  // ---- weight transpose+convert W[2048][C] -> WT[C][2048], 64x64 tiles
  const float* in; u16* out; int C; int tt;
  if      (blk < 5120){ in = wq; out = wqkvT;                     C = 2048; tt = blk - 4096; }
  else if (blk < 5376){ in = wk; out = wqkvT + (size_t)2048*2048; C = 512;  tt = blk - 5120; }
  else if (blk < 5632){ in = wv; out = wqkvT + (size_t)2560*2048; C = 512;  tt = blk - 5376; }
  else                 { in = wo; out = woT;                       C = 2048; tt = blk - 5632; }
  const int r0 = (tt & 31) * 64, c0 = (tt >> 5) * 64;    // 32 row-tiles (R=2048), C/64 col-tiles
  const int tx = tid & 63, ty = tid >> 6;                // (64,4)
  #pragma unroll
  for (int i = 0; i < 16; ++i)
    t[ty + i*4][tx] = in[(size_t)(r0 + ty + i*4) * C + c0 + tx];
  __syncthreads();
  #pragma unroll
  for (int i = 0; i < 16; ++i)
    out[(size_t)(c0 + ty + i*4) * 2048 + r0 + tx] = f2bf(t[tx][ty + i*4]);
}

// ================= fused post: rope(q) + rope(k) + V transpose =================
// ranges: [0,16384) rope q | [16384,20480) rope k | [20480,20992) tv (64x64 tiles)
#define POST_NBLK 20992
__global__ __launch_bounds__(256) void k_post(u16* __restrict__ qkv, u16* __restrict__ vtb,
                                              const float* __restrict__ cosT, const float* __restrict__ sinT,
                                              float qscale){
  __shared__ u16 tsh[64][66];   // pad 2: bank (tx + c/2) % 32 distinct across lanes
  const int blk = blockIdx.x, tid = threadIdx.x;
  if (blk < 20480){                                  // ---- RoPE + RMS-norm in place
    u16* base; int log2h; float scale; int rh;
    if (blk < 16384){ base = qkv;        log2h = 4; scale = qscale; rh = blk * 4 + (tid >> 6); }
    else            { base = qkv + 2048; log2h = 2; scale = 1.0f;   rh = (blk - 16384) * 4 + (tid >> 6); }
    const int lane = tid & 63;
    const int row = rh >> log2h;                     // b*T + t
    const int h   = rh & ((1 << log2h) - 1);
    const int t   = row & (T_SEQ - 1);
    u16* p = base + (size_t)row * QKVW + h * HD;
    float x1 = bf2f(p[lane]), x2 = bf2f(p[lane + 64]);
    float c = cosT[t * 64 + lane], s = sinT[t * 64 + lane];
    float y1 = x1 * c + x2 * s;
    float y2 = x2 * c - x1 * s;
    float sq = y1 * y1 + y2 * y2;
    #pragma unroll
    for (int off = 32; off; off >>= 1) sq += __shfl_xor(sq, off);
    float sc = rsqrtf(sq * (1.0f / 128.0f) + 1e-6f) * scale;
    p[lane]      = f2bf(y1 * sc);
    p[lane + 64] = f2bf(y2 * sc);
    return;
  }
  // ---- V transpose: per b, qkv[t][2560+c] -> vtb[b][c][t], 64x64 tiles
  const int tt = blk - 20480;                        // 0..511
  const int b  = tt >> 8;
  const int r0 = (tt & 31) * 64;                     // 32 row-tiles over T
  const int c0 = ((tt >> 5) & 7) * 64;               // 8 col-tiles over 512
  const u16* ib = qkv + (size_t)b * T_SEQ * QKVW + 2560;
  u16*       ob = vtb + (size_t)b * 512 * T_SEQ;
  const int tx = tid & 63, ty = tid >> 6;
  #pragma unroll
  for (int i = 0; i < 16; ++i)
    tsh[ty + i*4][tx] = ib[(size_t)(r0 + ty + i*4) * QKVW + c0 + tx];
  __syncthreads();
  #pragma unroll
  for (int i = 0; i < 16; ++i)
    ob[(size_t)(c0 + ty + i*4) * T_SEQ + r0 + tx] = tsh[tx][ty + i*4];
}

// ================= GEMM: 128x128 tile, BK=64 as 2 half-units, 3-slot LDS ring, counted vmcnt =================
// (validated R9/R12/R14: qkv ~59us, out ~39us, ~870 TF)
__device__ __forceinline__ void cstore(u16* C, size_t i, float v){ C[i] = f2bf(v); }
__device__ __forceinline__ void cstore(float* C, size_t i, float v){ C[i] = v; }

__device__ __forceinline__ void stage_half(const u16* __restrict__ G, int row0, int K, int k0,
                                           u16* lds, int w, int lane){
  #pragma unroll
  for (int call = 0; call < 2; ++call){
    const int o  = call * 256 + w * 64 + lane;   // chunk 0..511
    const int rp = o >> 3, sl = o & 7;
    const int lg = sl ^ (rp & 7);                // logical (h,kc)
    const int row = rp * 2 + (lg >> 2);
    const int kc  = lg & 3;
    g2lds16(G + (size_t)(row0 + row) * K + k0 + kc * 8, lds + (size_t)(call * 256 + w * 64) * 8);
  }
}

__device__ __forceinline__ s16x8 ldsFrag(const u16* slotBase, int row, int kchunk){
  const int byte = (row >> 1) * 128 + (((((row & 1) << 2) | kchunk) ^ ((row >> 1) & 7)) << 4);
  return *(const s16x8*)((const char*)slotBase + byte);
}

template <typename CT>
__global__ __launch_bounds__(256, 3) void k_gemm(const u16* __restrict__ A, const u16* __restrict__ BT,
                                                 CT* __restrict__ C, int M, int N, int K, int NPX){
  __shared__ u16 As[3 * 4096];   // 3 slots x 8KB
  __shared__ u16 Bs[3 * 4096];
  const int tid  = threadIdx.x;
  const int lane = tid & 63;
  const int w    = tid >> 6;
  const int wr = w >> 1, wc = w & 1;
  const int bid = blockIdx.x;
  const int xcd = bid & 7, ii = bid >> 3;
  const int ntile = xcd * NPX + ii % NPX;
  const int mtile = ii / NPX;
  const int tm0 = mtile * 128, tn0 = ntile * 128;
  const int frow = lane & 15, fk = lane >> 4;

  f32x4 acc[4][4] = {};
  const int nkt = K >> 6;

  stage_half(A,  tm0, K, 0,  As,        w, lane);
  stage_half(BT, tn0, K, 0,  Bs,        w, lane);
  stage_half(A,  tm0, K, 32, As + 4096, w, lane);
  stage_half(BT, tn0, K, 32, Bs + 4096, w, lane);
  asm volatile("s_waitcnt vmcnt(4)" ::: "memory");
  __builtin_amdgcn_s_barrier();

  int s = 0;
  #pragma unroll 1
  for (int t = 0; t < nkt; ++t){
    const int s1 = (s + 1 > 2) ? 0 : s + 1;
    const int s2 = (s + 2 > 2) ? s - 1 : s + 2;
    const bool more = (t + 1 < nkt);

    if (more){
      stage_half(A,  tm0, K, (t + 1) * 64,  As + s2 * 4096, w, lane);
      stage_half(BT, tn0, K, (t + 1) * 64,  Bs + s2 * 4096, w, lane);
    }
    {
      const u16* Ap = As + s * 4096;
      const u16* Bp = Bs + s * 4096;
      s16x8 af[4], bfr[4];
      #pragma unroll
      for (int m = 0; m < 4; ++m) af[m]  = ldsFrag(Ap, wr * 64 + m * 16 + frow, fk);
      #pragma unroll
      for (int n = 0; n < 4; ++n) bfr[n] = ldsFrag(Bp, wc * 64 + n * 16 + frow, fk);
      __builtin_amdgcn_s_setprio(1);
      #pragma unroll
      for (int m = 0; m < 4; ++m)
        #pragma unroll
        for (int n = 0; n < 4; ++n)
          acc[m][n] = __builtin_amdgcn_mfma_f32_16x16x32_bf16(af[m], bfr[n], acc[m][n], 0, 0, 0);
      __builtin_amdgcn_s_setprio(0);
    }
    if (more) asm volatile("s_waitcnt vmcnt(4)" ::: "memory");
    else      asm volatile("s_waitcnt vmcnt(0)" ::: "memory");
    __builtin_amdgcn_s_barrier();

    if (more){
      stage_half(A,  tm0, K, (t + 1) * 64 + 32, As + s * 4096, w, lane);
      stage_half(BT, tn0, K, (t + 1) * 64 + 32, Bs + s * 4096, w, lane);
    }
    {
      const u16* Ap = As + s1 * 4096;
      const u16* Bp = Bs + s1 * 4096;
      s16x8 af[4], bfr[4];
      #pragma unroll
      for (int m = 0; m < 4; ++m) af[m]  = ldsFrag(Ap, wr * 64 + m * 16 + frow, fk);
      #pragma unroll
      for (int n = 0; n < 4; ++n) bfr[n] = ldsFrag(Bp, wc * 64 + n * 16 + frow, fk);
      __builtin_amdgcn_s_setprio(1);
      #pragma unroll
      for (int m = 0; m < 4; ++m)
        #pragma unroll
        for (int n = 0; n < 4; ++n)
          acc[m][n] = __builtin_amdgcn_mfma_f32_16x16x32_bf16(af[m], bfr[n], acc[m][n], 0, 0, 0);
      __builtin_amdgcn_s_setprio(0);
    }
    if (more){
      asm volatile("s_waitcnt vmcnt(4)" ::: "memory");
      __builtin_amdgcn_s_barrier();
    }
    s = s2;
  }

  #pragma unroll
  for (int m = 0; m < 4; ++m){
    const int row0 = tm0 + wr * 64 + m * 16 + ((lane >> 4) << 2);
    #pragma unroll
    for (int n = 0; n < 4; ++n){
      const int col = tn0 + wc * 64 + n * 16 + (lane & 15);
      #pragma unroll
      for (int r = 0; r < 4; ++r)
        cstore(C, (size_t)(row0 + r) * N + col, acc[m][n][r]);
    }
  }
}

// ---------------- swizzled LDS fragment reads (byte ^= (row&7)<<4) ----------------
__device__ __forceinline__ s16x8 ldsK(const u16* base, int row, int colB){
  int a = row * 256 + colB; a ^= (row & 7) << 4;
  return *(const s16x8*)((const char*)base + a);
}
__device__ __forceinline__ s16x8 ldsV(const u16* base, int row, int colB){
  int a = row * 128 + colB; a ^= (row & 7) << 4;
  return *(const s16x8*)((const char*)base + a);
}

// ---------------- flash attention: 512 blocks x 4 waves, paired 64-row tiles, 2 blocks/CU ----------------
// (validated R10/R12/R14: 77.5us)
__global__ __launch_bounds__(256, 2) void k_attn(const u16* __restrict__ qkv, const u16* __restrict__ vt,
                                                 u16* __restrict__ yb){
  __shared__ u16 Kt[2][64 * 128];   // [key][d], 2 x 16 KB, XOR-swizzled
  __shared__ u16 Vt[2][128 * 64];   // V^T [d][key], 2 x 16 KB, XOR-swizzled
  const int tid = threadIdx.x, lane = tid & 63, w = tid >> 6;   // w = 0..3
  const int ql = lane & 31, hi = lane >> 5;

  const int bx  = blockIdx.x;                 // 0..511
  const int xcd = bx & 7;
  const int b   = xcd >> 2;
  const int kvh = xcd & 3;
  const int slot = bx >> 3;                   // 0..63
  const int hl  = slot >> 4;                  // 0..3
  const int p   = (slot + 5 * hl) & 15;       // decorrelated pair index
  const int h   = kvh * 4 + hl;

  const int tile = (w < 2) ? (31 - p) : p;    // 64-row tiles
  const int tq0  = tile * 64 + (w & 1) * 32;
  const int myq  = tq0 + ql;
  const int nkb  = 32 - p;                    // key-blocks for the big tile

  const u16* kg  = qkv + (size_t)(b * T_SEQ) * QKVW + 2048 + kvh * 128;
  const u16* vgb = vt + ((size_t)(b * 512 + kvh * 128)) * T_SEQ;

  auto stageK = [&](int kbI, u16* dst){
    const int ks = kbI * 64;
    #pragma unroll
    for (int cc = 0; cc < 4; ++cc){
      const int call = w * 4 + cc;             // 0..15
      const int o = call * 64 + lane;          // 16 chunks/row
      const int f = o ^ ((o >> 4) & 7);
      g2lds16(kg + (size_t)(ks + (o >> 4)) * QKVW + (f & 15) * 8, dst + call * 512);
    }
  };
  auto stageV = [&](int kbI, u16* dst){
    const int ks = kbI * 64;
    #pragma unroll
    for (int cc = 0; cc < 4; ++cc){
      const int call = w * 4 + cc;
      const int o = call * 64 + lane;          // 8 chunks/row, row = d
      const int f = o ^ ((o >> 3) & 7);
      g2lds16(vgb + (size_t)(o >> 3) * T_SEQ + ks + (f & 7) * 8, dst + call * 512);
    }
  };

  // prologue: stage K(0),V(0) into buffers [0]
  stageK(0, Kt[0]);
  stageV(0, Vt[0]);

  const u16* qrow = qkv + ((size_t)(b * T_SEQ + myq)) * QKVW + h * HD + hi * 8;
  s16x8 qf[8];
  #pragma unroll
  for (int kc = 0; kc < 8; ++kc) qf[kc] = *(const s16x8*)(qrow + kc * 16);

  f32x16 O[4] = {};
  float mloc = -1e30f, lloc = 0.0f;

  asm volatile("s_waitcnt vmcnt(0)" ::: "memory");
  __builtin_amdgcn_s_barrier();

  for (int kbI = 0; kbI < nkb; ++kbI){
    const int ks  = kbI * 64;
    const int cur = kbI & 1;

    // issue next tile's staging into the other buffers
    if (kbI + 1 < nkb){
      stageV(kbI + 1, Vt[cur ^ 1]);
      stageK(kbI + 1, Kt[cur ^ 1]);
    }

    if (ks <= tq0 + 31){
      const u16* Kc = Kt[cur];
      const u16* Vc = Vt[cur];
      const bool doN1 = (ks + 32 <= tq0 + 31);
      f32x16 S0 = {}, S1 = {};
      __builtin_amdgcn_s_setprio(1);
      #pragma unroll
      for (int kc = 0; kc < 8; ++kc)
        S0 = __builtin_amdgcn_mfma_f32_32x32x16_bf16(ldsK(Kc, ql, kc*32 + hi*16), qf[kc], S0, 0, 0, 0);
      if (doN1){
        #pragma unroll
        for (int kc = 0; kc < 8; ++kc)
          S1 = __builtin_amdgcn_mfma_f32_32x32x16_bf16(ldsK(Kc, 32 + ql, kc*32 + hi*16), qf[kc], S1, 0, 0, 0);
      }
      __builtin_amdgcn_s_setprio(0);
      // causal mask; key(r) = ks + ntile*32 + (r&3) + 8*(r>>2) + 4*hi
      if (ks + 31 > tq0){
        #pragma unroll
        for (int r = 0; r < 16; ++r)
          if (ks + (r&3) + 8*(r>>2) + 4*hi > myq) S0[r] = -1e30f;
      }
      if (doN1 && (ks + 63 > tq0)){
        #pragma unroll
        for (int r = 0; r < 16; ++r)
          if (ks + 32 + (r&3) + 8*(r>>2) + 4*hi > myq) S1[r] = -1e30f;
      }
      float mr = -1e30f;
      #pragma unroll
      for (int r = 0; r < 16; ++r) mr = fmaxf(mr, S0[r]);
      if (doN1){
        #pragma unroll
        for (int r = 0; r < 16; ++r) mr = fmaxf(mr, S1[r]);
      }
      mr = fmaxf(mr, __shfl_xor(mr, 32));
      if (!__all(mr <= mloc + 8.0f)){       // defer-max (T13)
        const float mn = fmaxf(mloc, mr);
        const float a  = __expf(mloc - mn);
        mloc = mn; lloc *= a;
        #pragma unroll
        for (int dt = 0; dt < 4; ++dt)
          #pragma unroll
          for (int r = 0; r < 16; ++r) O[dt][r] *= a;
      }
      float rs = 0.0f;
      #pragma unroll
      for (int r = 0; r < 16; ++r){ S0[r] = __expf(S0[r] - mloc); rs += S0[r]; }
      if (doN1){
        #pragma unroll
        for (int r = 0; r < 16; ++r){ S1[r] = __expf(S1[r] - mloc); rs += S1[r]; }
      }
      rs += __shfl_xor(rs, 32);
      lloc += rs;
      // pack P^T -> PV B-frags
      u32 bw[16];
      {
        u32 pk[8], pp[8];
        #pragma unroll
        for (int j = 0; j < 8; ++j) pk[j] = pkbf(S0[2*j], S0[2*j+1]);
        #pragma unroll
        for (int j = 0; j < 8; ++j) pp[j] = (u32)__shfl_xor((int)pk[j], 32);
        bw[0] = hi ? pp[2] : pk[0];  bw[1] = hi ? pp[3] : pk[1];
        bw[2] = hi ? pk[2] : pp[0];  bw[3] = hi ? pk[3] : pp[1];
        bw[4] = hi ? pp[6] : pk[4];  bw[5] = hi ? pp[7] : pk[5];
        bw[6] = hi ? pk[6] : pp[4];  bw[7] = hi ? pk[7] : pp[5];
      }
      int nkc = 2;
      if (doN1){
        u32 pk[8], pp[8];
        #pragma unroll
        for (int j = 0; j < 8; ++j) pk[j] = pkbf(S1[2*j], S1[2*j+1]);
        #pragma unroll
        for (int j = 0; j < 8; ++j) pp[j] = (u32)__shfl_xor((int)pk[j], 32);
        bw[8]  = hi ? pp[2] : pk[0];  bw[9]  = hi ? pp[3] : pk[1];
        bw[10] = hi ? pk[2] : pp[0];  bw[11] = hi ? pk[3] : pp[1];
        bw[12] = hi ? pp[6] : pk[4];  bw[13] = hi ? pp[7] : pk[5];
        bw[14] = hi ? pk[6] : pp[4];  bw[15] = hi ? pk[7] : pp[5];
        nkc = 4;
      }
      // PV directly from Vt[cur]
      __builtin_amdgcn_s_setprio(1);
      #pragma unroll
      for (int kc = 0; kc < 4; ++kc){
        if (kc < nkc){
          union { u32 u[4]; s16x8 v; } pb;
          pb.u[0] = bw[kc*4+0]; pb.u[1] = bw[kc*4+1]; pb.u[2] = bw[kc*4+2]; pb.u[3] = bw[kc*4+3];
          #pragma unroll
          for (int dt = 0; dt < 4; ++dt)
            O[dt] = __builtin_amdgcn_mfma_f32_32x32x16_bf16(ldsV(Vc, dt*32 + ql, kc*32 + hi*16), pb.v, O[dt], 0, 0, 0);
        }
      }
      __builtin_amdgcn_s_setprio(0);
    }

    // single sync point: next buffers landed; all waves done with current buffers
    asm volatile("s_waitcnt vmcnt(0)" ::: "memory");
    __builtin_amdgcn_s_barrier();
  }

  // epilogue: normalize, pack, store
  const float linv = 1.0f / lloc;
  u16* yr = yb + ((size_t)(b * T_SEQ + myq)) * NE + h * HD;
  #pragma unroll
  for (int dt = 0; dt < 4; ++dt){
    #pragma unroll
    for (int mq = 0; mq < 4; ++mq){
      uint2 s;
      s.x = pkbf(O[dt][4*mq+0] * linv, O[dt][4*mq+1] * linv);
      s.y = pkbf(O[dt][4*mq+2] * linv, O[dt][4*mq+3] * linv);
      *(uint2*)(yr + dt*32 + 8*mq + 4*hi) = s;
    }
  }
}

// ---------------- launch ----------------
extern "C" void kernel_launch(void* const* d_in, const int* in_sizes, int n_in,
                              void* d_out, int out_size, void* d_ws, size_t ws_size,
                              hipStream_t stream){
  const float* x  = (const float*)d_in[0];
  const float* wq = (const float*)d_in[1];
  const float* wk = (const float*)d_in[2];
  const float* wv = (const float*)d_in[3];
  const float* wo = (const float*)d_in[4];
  float* out = (float*)d_out;

  char* w = (char*)d_ws;
  u16* xb    = (u16*)w;  w += (size_t)4096 * 2048 * 2;   // 16 MB
  u16* wqkvT = (u16*)w;  w += (size_t)3072 * 2048 * 2;   // 12 MB
  u16* woT   = (u16*)w;  w += (size_t)2048 * 2048 * 2;   //  8 MB
  u16* qkv   = (u16*)w;  w += (size_t)4096 * 3072 * 2;   // 24 MB
  u16* vtb   = (u16*)w;  w += (size_t)4096 * 512  * 2;   //  4 MB
  u16* yb    = (u16*)w;  w += (size_t)4096 * 2048 * 2;   // 16 MB
  float* cosT = (float*)w; w += (size_t)2048 * 64 * 4;   // 0.5 MB
  float* sinT = (float*)w; w += (size_t)2048 * 64 * 4;   // 0.5 MB

  const float SCALE = 0.08838834764831845f;  // 1/sqrt(128), folded into q

  // 1) fused prep (64x64 transposes, 8/thread cvt)
  k_prep<<<PREP_NBLK, 256, 0, stream>>>(x, wq, wk, wv, wo, xb, wqkvT, woT, cosT, sinT);

  // 2) fused QKV projection: [4096][3072]  (768 blocks, NPX=3, 3 blocks/CU uniform)
  k_gemm<u16><<<768, 256, 0, stream>>>(xb, wqkvT, qkv, 4096, QKVW, 2048, 3);

  // 3) fused post: RoPE q/k + V transpose (64x64 tiles)
  k_post<<<POST_NBLK, 256, 0, stream>>>(qkv, vtb, cosT, sinT, SCALE);

  // 4) causal flash attention (512 x 4-wave paired blocks, 2 blocks/CU)
  k_attn<<<512, 256, 0, stream>>>(qkv, vtb, yb);

  // 5) output projection -> fp32  (512 blocks, NPX=2, 2 blocks/CU uniform)
  k_gemm<float><<<512, 256, 0, stream>>>(yb, woT, out, 4096, 2048, 2048, 2);
}